// Round 1
// baseline (227.598 us; speedup 1.0000x reference)
//
#include <hip/hip_runtime.h>
#include <hip/hip_bf16.h>

typedef unsigned short u16;
typedef short short8 __attribute__((ext_vector_type(8)));
typedef float floatx4 __attribute__((ext_vector_type(4)));

#define MFMA16(a, b, c) __builtin_amdgcn_mfma_f32_16x16x32_bf16((a), (b), (c), 0, 0, 0)

union U64u { unsigned long long ll; u16 s[4]; };
union U128u { uint4 q; u16 s[8]; };

__device__ __forceinline__ u16 f2bf(float f) {
  union { float f; unsigned u; } v; v.f = f;
  unsigned r = v.u + 0x7fffu + ((v.u >> 16) & 1u);
  return (u16)(r >> 16);
}

// async global->LDS, 16B per lane. lds pointer must be wave-uniform.
__device__ __forceinline__ void async16(const u16* g, u16* l) {
  __builtin_amdgcn_global_load_lds(
      (const __attribute__((address_space(1))) unsigned int*)g,
      (__attribute__((address_space(3))) unsigned int*)l, 16, 0, 0);
}

// ---------------- prep kernels ----------------

__global__ __launch_bounds__(256) void cast_f2b(const float* __restrict__ src,
                                                u16* __restrict__ dst, int n4) {
  int i = blockIdx.x * 256 + threadIdx.x;
  if (i >= n4) return;
  float4 v = ((const float4*)src)[i];
  U64u o;
  o.s[0] = f2bf(v.x); o.s[1] = f2bf(v.y); o.s[2] = f2bf(v.z); o.s[3] = f2bf(v.w);
  ((unsigned long long*)dst)[i] = o.ll;
}

// Build W_allT [3072(n), 1024(d)] bf16 from Wq/Wk/Wv [16,1024,64] fp32, + bias_all fp32[3072]
__global__ __launch_bounds__(256) void prep_wqkv(
    const float* __restrict__ Wq, const float* __restrict__ bq,
    const float* __restrict__ Wk, const float* __restrict__ bk,
    const float* __restrict__ Wv, const float* __restrict__ bv,
    u16* __restrict__ Wt, float* __restrict__ ball) {
  int id = blockIdx.x * 256 + threadIdx.x;  // 786432 total
  int kk4 = id & 15;
  int d = (id >> 4) & 1023;
  int h = (id >> 14) & 15;
  int wsel = id >> 18;
  const float* W = wsel == 0 ? Wq : (wsel == 1 ? Wk : Wv);
  float4 v = *(const float4*)(W + ((size_t)(h * 1024 + d)) * 64 + kk4 * 4);
  int nb = wsel * 1024 + h * 64 + kk4 * 4;
  Wt[(size_t)(nb + 0) * 1024 + d] = f2bf(v.x);
  Wt[(size_t)(nb + 1) * 1024 + d] = f2bf(v.y);
  Wt[(size_t)(nb + 2) * 1024 + d] = f2bf(v.z);
  Wt[(size_t)(nb + 3) * 1024 + d] = f2bf(v.w);
  if (id < 3072) {
    int ws2 = id >> 10, hk = id & 1023;
    const float* bsrc = ws2 == 0 ? bq : (ws2 == 1 ? bk : bv);
    ball[id] = bsrc[hk];
  }
}

// Vt[b,h,d,s] <- QKV[(b*2048+s)*3072 + 2048 + h*64 + d]
__global__ __launch_bounds__(256) void transpose_v(const u16* __restrict__ QKV,
                                                   u16* __restrict__ Vt) {
  __shared__ u16 t[64][65];
  int tid = threadIdx.x;
  int bh = blockIdx.y, b = bh >> 4, h = bh & 15;
  int s0 = blockIdx.x * 64;
  {
    int r = tid >> 2, c0 = (tid & 3) * 16;
    const u16* src = QKV + (size_t)(b * 2048 + s0 + r) * 3072 + 2048 + h * 64 + c0;
    U128u a, c;
    a.q = *(const uint4*)src;
    c.q = *(const uint4*)(src + 8);
#pragma unroll
    for (int j = 0; j < 8; ++j) { t[r][c0 + j] = a.s[j]; t[r][c0 + 8 + j] = c.s[j]; }
  }
  __syncthreads();
  {
    int dl = tid >> 2, sp = (tid & 3) * 16;
    U128u oa, ob;
#pragma unroll
    for (int j = 0; j < 8; ++j) { oa.s[j] = t[sp + j][dl]; ob.s[j] = t[sp + 8 + j][dl]; }
    u16* dst = Vt + (size_t)(bh * 64 + dl) * 2048 + s0 + sp;
    *(uint4*)dst = oa.q;
    *(uint4*)(dst + 8) = ob.q;
  }
}

// ---------------- GEMM: C[M,N] = A[M,K] * B^T (B stored [N,K]) + bias, opt scale ----------------

__device__ __forceinline__ void store_out(u16* p, float v) { *p = f2bf(v); }
__device__ __forceinline__ void store_out(float* p, float v) { *p = v; }

template <typename OutT>
__global__ __launch_bounds__(256) void gemm_bt(
    const u16* __restrict__ A, const u16* __restrict__ B,
    const float* __restrict__ bias, OutT* __restrict__ C,
    int M, int N, int K, int scaleNend, float scaleVal) {
  __shared__ __attribute__((aligned(16))) u16 As[128 * 32];
  __shared__ __attribute__((aligned(16))) u16 Bs[128 * 32];
  const int tid = threadIdx.x;
  const int w = tid >> 6, lane = tid & 63;
  const int l15 = lane & 15, l4 = lane >> 4;
  const int bm = blockIdx.y, bn = blockIdx.x;
  const int wm = (w & 1) * 64, wn = (w >> 1) * 64;

  floatx4 acc[4][4];
#pragma unroll
  for (int i = 0; i < 4; ++i)
#pragma unroll
    for (int j = 0; j < 4; ++j) acc[i][j] = (floatx4){0.f, 0.f, 0.f, 0.f};

  for (int k0 = 0; k0 < K; k0 += 32) {
    __syncthreads();
#pragma unroll
    for (int j = 0; j < 2; ++j) {
      int c = j * 4 + w;
      int row = c * 16 + (lane >> 2);
      int ko = (lane & 3) * 8;
      async16(A + (size_t)(bm * 128 + row) * K + k0 + ko, As + c * 512);
      async16(B + (size_t)(bn * 128 + row) * K + k0 + ko, Bs + c * 512);
    }
    __syncthreads();
    short8 af[4], bf[4];
#pragma unroll
    for (int t = 0; t < 4; ++t) {
      af[t] = *(const short8*)(As + (wm + t * 16 + l15) * 32 + l4 * 8);
      bf[t] = *(const short8*)(Bs + (wn + t * 16 + l15) * 32 + l4 * 8);
    }
#pragma unroll
    for (int tm = 0; tm < 4; ++tm)
#pragma unroll
      for (int tn = 0; tn < 4; ++tn) acc[tm][tn] = MFMA16(af[tm], bf[tn], acc[tm][tn]);
  }

#pragma unroll
  for (int tn = 0; tn < 4; ++tn) {
    int col = bn * 128 + wn + tn * 16 + l15;
    float bv = bias[col];
    float sc = (col < scaleNend) ? scaleVal : 1.0f;
#pragma unroll
    for (int tm = 0; tm < 4; ++tm) {
      int row0 = bm * 128 + wm + tm * 16 + l4 * 4;
#pragma unroll
      for (int r = 0; r < 4; ++r) {
        float v = (acc[tm][tn][r] + bv) * sc;
        store_out(C + (size_t)(row0 + r) * N + col, v);
      }
    }
  }
}

// ---------------- attention: O[4096,1024] (concat heads), unnormalized-exp flash ----------------
// Q is pre-scaled by 1/8 (exact pow2) in the QKV GEMM epilogue.

__global__ __launch_bounds__(256) void attn_kernel(const u16* __restrict__ QKV,
                                                   const u16* __restrict__ Vt,
                                                   u16* __restrict__ O) {
  __shared__ __attribute__((aligned(16))) u16 Ks[128 * 64];    // [key][d], 8-elem chunks XOR-swizzled by key&7
  __shared__ __attribute__((aligned(16))) u16 Vs[64 * 128];    // [d][key], 8-elem chunks XOR-swizzled by d&15
  __shared__ __attribute__((aligned(16))) u16 Ps[128 * 136];   // [q][key], +8 pad

  const int tid = threadIdx.x;
  const int w = tid >> 6, lane = tid & 63;
  const int l15 = lane & 15, l4 = lane >> 4;
  const int q0 = blockIdx.x * 128;
  const int bh = blockIdx.y;
  const int b = bh >> 4, h = bh & 15;

  // Q fragments (B-operand of S^T mfma): rows w*32 + tq*16 + l15, k chunks over head dim
  short8 qf[2][2];
  {
    const u16* Qb = QKV + (size_t)(b * 2048 + q0 + w * 32) * 3072 + h * 64;
#pragma unroll
    for (int tq = 0; tq < 2; ++tq)
#pragma unroll
      for (int kc = 0; kc < 2; ++kc)
        qf[tq][kc] = *(const short8*)(Qb + (size_t)(tq * 16 + l15) * 3072 + kc * 32 + l4 * 8);
  }

  floatx4 Oacc[2][4];
#pragma unroll
  for (int i = 0; i < 2; ++i)
#pragma unroll
    for (int j = 0; j < 4; ++j) Oacc[i][j] = (floatx4){0.f, 0.f, 0.f, 0.f};
  float lpart[2] = {0.f, 0.f};

  const u16* Kb = QKV + (size_t)(b * 2048) * 3072 + 1024 + h * 64;
  const u16* Vb = Vt + (size_t)bh * 64 * 2048;

  for (int kt = 0; kt < 16; ++kt) {
    __syncthreads();
#pragma unroll
    for (int j = 0; j < 4; ++j) {
      int c = j * 4 + w;
      {
        int row = c * 8 + (lane >> 3);
        int gch = (lane & 7) ^ ((lane >> 3) & 7);
        async16(Kb + (size_t)(kt * 128 + row) * 3072 + gch * 8, Ks + c * 512);
      }
      {
        int d = c * 4 + l4;
        int gch = l15 ^ (d & 15);
        async16(Vb + (size_t)d * 2048 + kt * 128 + gch * 8, Vs + c * 512);
      }
    }
    __syncthreads();

    // S^T tiles: mfma(A=K[key][hd], B=Q^T[hd][q]) -> C[key][q]; col=q=l15, row=key=l4*4+r
#pragma unroll
    for (int tk = 0; tk < 8; ++tk) {
      int krow = tk * 16 + l15;
      int sw = krow & 7;
      short8 kf0 = *(const short8*)(Ks + krow * 64 + ((l4) ^ sw) * 8);
      short8 kf1 = *(const short8*)(Ks + krow * 64 + ((4 + l4) ^ sw) * 8);
#pragma unroll
      for (int tq = 0; tq < 2; ++tq) {
        floatx4 s = (floatx4){0.f, 0.f, 0.f, 0.f};
        s = MFMA16(kf0, qf[tq][0], s);
        s = MFMA16(kf1, qf[tq][1], s);
        U64u pk;
#pragma unroll
        for (int r = 0; r < 4; ++r) {
          float p = __expf(s[r]);  // scores pre-scaled by 1/8; flat softmax, no max needed
          lpart[tq] += p;
          pk.s[r] = f2bf(p);
        }
        // P[q][key]: q = w*32+tq*16+l15, keys tk*16+l4*4 .. +4 (contiguous 8B)
        *(unsigned long long*)(Ps + (size_t)(w * 32 + tq * 16 + l15) * 136 + tk * 16 + l4 * 4) = pk.ll;
      }
    }

    // PV: O[q][d] += P[q][key] * V[key][d]; A=P (own-wave rows), B=V^T in Vs
    short8 pf[2][4];
#pragma unroll
    for (int tq = 0; tq < 2; ++tq)
#pragma unroll
      for (int kc = 0; kc < 4; ++kc)
        pf[tq][kc] = *(const short8*)(Ps + (size_t)(w * 32 + tq * 16 + l15) * 136 + kc * 32 + l4 * 8);
#pragma unroll
    for (int td = 0; td < 4; ++td)
#pragma unroll
      for (int kc = 0; kc < 4; ++kc) {
        int drow = td * 16 + l15;
        short8 vf = *(const short8*)(Vs + drow * 128 + (((kc << 2) | l4) ^ l15) * 8);
#pragma unroll
        for (int tq = 0; tq < 2; ++tq) Oacc[tq][td] = MFMA16(pf[tq][kc], vf, Oacc[tq][td]);
      }
  }

  // reduce l over the 4 lane-groups (keys were split by l4), then redistribute to C-layout rows
  float linv[2];
#pragma unroll
  for (int tq = 0; tq < 2; ++tq) {
    float l = lpart[tq];
    l += __shfl_xor(l, 16);
    l += __shfl_xor(l, 32);
    linv[tq] = 1.0f / l;  // valid for q = w*32 + tq*16 + l15
  }
  float iv[2][4];
#pragma unroll
  for (int tq = 0; tq < 2; ++tq)
#pragma unroll
    for (int r = 0; r < 4; ++r) iv[tq][r] = __shfl(linv[tq], l4 * 4 + r);

  u16* Ob = O + (size_t)(b * 2048 + q0 + w * 32) * 1024 + h * 64;
#pragma unroll
  for (int tq = 0; tq < 2; ++tq)
#pragma unroll
    for (int td = 0; td < 4; ++td)
#pragma unroll
      for (int r = 0; r < 4; ++r)
        Ob[(size_t)(tq * 16 + l4 * 4 + r) * 1024 + td * 16 + l15] =
            f2bf(Oacc[tq][td][r] * iv[tq][r]);
}

// ---------------- launch ----------------

extern "C" void kernel_launch(void* const* d_in, const int* in_sizes, int n_in,
                              void* d_out, int out_size, void* d_ws, size_t ws_size,
                              hipStream_t stream) {
  const float* x  = (const float*)d_in[0];
  const float* Wq = (const float*)d_in[1];
  const float* bq = (const float*)d_in[2];
  const float* Wk = (const float*)d_in[3];
  const float* bk = (const float*)d_in[4];
  const float* Wv = (const float*)d_in[5];
  const float* bv = (const float*)d_in[6];
  const float* Wo = (const float*)d_in[7];
  const float* bo = (const float*)d_in[8];

  char* p = (char*)d_ws;
  u16* Xb   = (u16*)p; p += (size_t)4096 * 1024 * 2;   // x bf16
  u16* Wt   = (u16*)p; p += (size_t)3072 * 1024 * 2;   // W_all^T bf16 [n][d]
  u16* QKV  = (u16*)p; p += (size_t)4096 * 3072 * 2;   // [token][3072] bf16 (Q pre-scaled 1/8)
  u16* Vtp  = (u16*)p; p += (size_t)2 * 16 * 64 * 2048 * 2;  // V^T per (b,h): [d][s]
  u16* Ob   = (u16*)p; p += (size_t)4096 * 1024 * 2;   // attention out bf16
  u16* Wob  = (u16*)p; p += (size_t)1024 * 1024 * 2;   // Wo bf16 [e][d]
  float* ball = (float*)p; p += 3072 * sizeof(float);

  cast_f2b<<<4096, 256, 0, stream>>>(x, Xb, 1048576);
  cast_f2b<<<1024, 256, 0, stream>>>(Wo, Wob, 262144);
  prep_wqkv<<<3072, 256, 0, stream>>>(Wq, bq, Wk, bk, Wv, bv, Wt, ball);
  gemm_bt<u16><<<dim3(24, 32), 256, 0, stream>>>(Xb, Wt, ball, QKV,
                                                 4096, 3072, 1024, 1024, 0.125f);
  transpose_v<<<dim3(32, 32), 256, 0, stream>>>(QKV, Vtp);
  attn_kernel<<<dim3(16, 32), 256, 0, stream>>>(QKV, Vtp, Ob);
  gemm_bt<float><<<dim3(8, 32), 256, 0, stream>>>(Ob, Wob, bo, (float*)d_out,
                                                  4096, 1024, 1024, 0, 1.0f);
}